// Round 1
// baseline (8125.072 us; speedup 1.0000x reference)
//
// ProbMPS on MI355X — R1 baseline.
// Design: (1) mps_norm: bidirectional transfer-matrix scan, 128 blocks (64 fwd d-blocks,
// 64 bwd d-blocks), bf16 MFMA 16x16x32, per-step /64 rescale (no trace on critical path),
// split-phase d-reduction + custom agent-scope grid barrier (2 per round x 128 rounds).
// (2) mps_batch: 256 blocks, one batch chain each, fp32 LDS-staged matvec with register
// prefetch pipeline. (3) tiny init/final kernels.
// ws usage: cnt(4B) @0, psi2[256]f32 @1024, rho bf16[16384] @4096, sig @36864,
// P f32[128][16384] @131072  => needs ~8.5 MiB of ws.
#include <hip/hip_runtime.h>
#include <cstddef>

#define SEQ 256
#define IDIM 64
#define BD 128
#define NB 256
#define TS 136              // bf16 elems per LDS tile row (272B: 16B-aligned, conflict-friendly)
#define NORM_BLOCKS 128
#define ROUNDS 128

#define WS_CNT 0
#define WS_PSI 1024
#define WS_RHO 4096
#define WS_SIG 36864
#define WS_P   131072

typedef float float4v __attribute__((ext_vector_type(4)));
typedef short short8v __attribute__((ext_vector_type(8)));
typedef unsigned short ushort_t;

__device__ __forceinline__ ushort_t f2bf(float x) {
    unsigned int u = __builtin_bit_cast(unsigned int, x);
    return (ushort_t)((u + 0x7FFFu + ((u >> 16) & 1u)) >> 16);   // RNE
}
__device__ __forceinline__ float bf2f(ushort_t h) {
    unsigned int u = ((unsigned int)h) << 16;
    return __builtin_bit_cast(float, u);
}
__device__ __forceinline__ float4v mfma16(short8v a, short8v b, float4v c) {
    return __builtin_amdgcn_mfma_f32_16x16x32_bf16(a, b, c, 0, 0, 0);
}

// Monotonic-counter device barrier over NORM_BLOCKS blocks (all co-resident: 128 blocks,
// 1/CU by LDS, 256 CUs). Release on arrive (wbL2), relaxed spin, acquire on exit (invL1/L2).
__device__ __forceinline__ void grid_bar(unsigned int* cnt, unsigned int target) {
    __syncthreads();
    if (threadIdx.x == 0) {
        __hip_atomic_fetch_add(cnt, 1u, __ATOMIC_RELEASE, __HIP_MEMORY_SCOPE_AGENT);
        while (__hip_atomic_load(cnt, __ATOMIC_RELAXED, __HIP_MEMORY_SCOPE_AGENT) < target) {
            __builtin_amdgcn_s_sleep(1);
        }
        (void)__hip_atomic_load(cnt, __ATOMIC_ACQUIRE, __HIP_MEMORY_SCOPE_AGENT);
    }
    __syncthreads();
}

__global__ void mps_init(const float* __restrict__ edge, unsigned char* __restrict__ ws) {
    unsigned int* cnt = (unsigned int*)(ws + WS_CNT);
    ushort_t* rho = (ushort_t*)(ws + WS_RHO);
    ushort_t* sig = (ushort_t*)(ws + WS_SIG);
    int tid = threadIdx.x;
    if (tid == 0) *cnt = 0u;
    __shared__ float al[BD], om[BD];
    if (tid < BD) { al[tid] = edge[tid]; om[tid] = edge[BD + tid]; }
    __syncthreads();
    for (int i = tid; i < BD * BD; i += 256) {
        int r = i >> 7, c = i & 127;
        rho[i] = f2bf(al[r] * al[c]);    // rho0 = alpha alpha^T
        sig[i] = f2bf(om[r] * om[c]);    // sig0 = omega omega^T
    }
}

// ---- norm kernel: per round, fwd block d does P_d = A_d rho A_d^T (t ascending),
// bwd block d does Q_d = A_d^T sig A_d (t descending), via Abar = A^T (identity-MFMA).
// Then all-reduce over d (each block owns 2 rows), scale 1/64, store bf16 state.
__global__ __launch_bounds__(256, 1) void mps_norm(const float* __restrict__ core,
                                                   unsigned char* __restrict__ ws) {
    extern __shared__ unsigned char smem[];
    ushort_t* tA = (ushort_t*)smem;      // raw A (row-major, stride TS)
    ushort_t* tS = tA + BD * TS;         // state (rho or sigma), symmetric
    ushort_t* tC = tS + BD * TS;         // fwd: Bmat scratch | bwd: Abar (=A^T)

    unsigned int* cnt = (unsigned int*)(ws + WS_CNT);
    ushort_t* rho = (ushort_t*)(ws + WS_RHO);
    ushort_t* sig = (ushort_t*)(ws + WS_SIG);
    float* P = (float*)(ws + WS_P);

    const int bid = blockIdx.x;
    const int dir = bid >> 6;            // 0 fwd, 1 bwd
    const int d = bid & 63;
    const int tid = threadIdx.x;
    const int w = tid >> 6;              // wave 0..3 -> output rows 32w..32w+31
    const int m = tid & 15;
    const int q = (tid & 63) >> 4;       // quad within wave

    ushort_t* stateG = dir ? sig : rho;
    float* Pmine = P + (size_t)bid * (BD * BD);
    const float* Pgrp = P + (size_t)(dir ? 64 : 0) * (BD * BD);

    unsigned int bar = 0;

    for (int s = 0; s < ROUNDS; ++s) {
        const int t = dir ? (SEQ - 1 - s) : s;
        const float* A = core + ((size_t)(t * IDIM + d) << 14);

        // stage A (fp32 global -> bf16 LDS row-major)
        {
            const float4v* A4 = (const float4v*)A;
            #pragma unroll
            for (int s2 = 0; s2 < 16; ++s2) {
                int f = s2 * 256 + tid;          // float4 idx 0..4095
                int i = f >> 5;
                int j = (f & 31) << 2;
                float4v v = A4[f];
                unsigned long long pk = (unsigned long long)f2bf(v.x)
                                      | ((unsigned long long)f2bf(v.y) << 16)
                                      | ((unsigned long long)f2bf(v.z) << 32)
                                      | ((unsigned long long)f2bf(v.w) << 48);
                *(unsigned long long*)(tA + i * TS + j) = pk;
            }
        }
        // stage state (bf16 global -> LDS)
        {
            const unsigned int* Sg = (const unsigned int*)stateG;
            #pragma unroll
            for (int s2 = 0; s2 < 32; ++s2) {
                int f = s2 * 256 + tid;          // uint idx 0..8191
                int r = f >> 6;
                int c = (f & 63) << 1;
                *(unsigned int*)(tS + r * TS + c) = Sg[f];
            }
        }
        __syncthreads();

        if (dir) {
            // tC = A^T: D = I * (tA read as B-operand => effective A^T). Only the k-window
            // intersecting the output rows contributes (identity is block-diagonal).
            #pragma unroll
            for (int rt = 0; rt < 2; ++rt) {
                short8v ifr;
                #pragma unroll
                for (int j = 0; j < 8; ++j)
                    ifr[j] = (short)(((q * 8 + j) == (rt * 16 + m)) ? 0x3F80 : 0);
                #pragma unroll
                for (int ct = 0; ct < 8; ++ct) {
                    short8v bf = *(const short8v*)(tA + (ct * 16 + m) * TS + w * 32 + q * 8);
                    float4v ac = {0.f, 0.f, 0.f, 0.f};
                    ac = mfma16(ifr, bf, ac);
                    int col = ct * 16 + m;
                    #pragma unroll
                    for (int r = 0; r < 4; ++r) {
                        int row = 32 * w + 16 * rt + 4 * q + r;
                        tC[row * TS + col] = f2bf(ac[r]);
                    }
                }
            }
            __syncthreads();
        }

        {
            // mm1: Bmat = L * state   (L rows = this wave's 32 rows)
            const ushort_t* L = dir ? tC : tA;
            ushort_t* OB = dir ? tA : tC;        // bwd aliases raw-A (no longer needed)
            float4v acc[2][8];
            #pragma unroll
            for (int rt = 0; rt < 2; ++rt)
                #pragma unroll
                for (int ct = 0; ct < 8; ++ct) acc[rt][ct] = {0.f, 0.f, 0.f, 0.f};
            #pragma unroll
            for (int kk = 0; kk < 4; ++kk) {
                short8v a0 = *(const short8v*)(L + (32 * w + m) * TS + kk * 32 + q * 8);
                short8v a1 = *(const short8v*)(L + (32 * w + 16 + m) * TS + kk * 32 + q * 8);
                #pragma unroll
                for (int ct = 0; ct < 8; ++ct) {
                    // B-operand reads tS[n][k] => effective state^T = state (symmetric)
                    short8v b = *(const short8v*)(tS + (ct * 16 + m) * TS + kk * 32 + q * 8);
                    acc[0][ct] = mfma16(a0, b, acc[0][ct]);
                    acc[1][ct] = mfma16(a1, b, acc[1][ct]);
                }
            }
            #pragma unroll
            for (int rt = 0; rt < 2; ++rt)
                #pragma unroll
                for (int ct = 0; ct < 8; ++ct) {
                    int col = ct * 16 + m;
                    #pragma unroll
                    for (int r = 0; r < 4; ++r) {
                        int row = 32 * w + 16 * rt + 4 * q + r;
                        OB[row * TS + col] = f2bf(acc[rt][ct][r]);
                    }
                }
            // mm2: P_d = Bmat * R2^T  (B-operand trick: memory R2 row-major => effective R2^T)
            const ushort_t* L2 = OB;
            const ushort_t* R2 = dir ? tC : tA;
            #pragma unroll
            for (int rt = 0; rt < 2; ++rt)
                #pragma unroll
                for (int ct = 0; ct < 8; ++ct) acc[rt][ct] = {0.f, 0.f, 0.f, 0.f};
            #pragma unroll
            for (int kk = 0; kk < 4; ++kk) {
                short8v a0 = *(const short8v*)(L2 + (32 * w + m) * TS + kk * 32 + q * 8);
                short8v a1 = *(const short8v*)(L2 + (32 * w + 16 + m) * TS + kk * 32 + q * 8);
                #pragma unroll
                for (int ct = 0; ct < 8; ++ct) {
                    short8v b = *(const short8v*)(R2 + (ct * 16 + m) * TS + kk * 32 + q * 8);
                    acc[0][ct] = mfma16(a0, b, acc[0][ct]);
                    acc[1][ct] = mfma16(a1, b, acc[1][ct]);
                }
            }
            #pragma unroll
            for (int rt = 0; rt < 2; ++rt)
                #pragma unroll
                for (int ct = 0; ct < 8; ++ct) {
                    int col = ct * 16 + m;
                    #pragma unroll
                    for (int r = 0; r < 4; ++r) {
                        int row = 32 * w + 16 * rt + 4 * q + r;
                        Pmine[row * BD + col] = acc[rt][ct][r];
                    }
                }
        }

        ++bar; grid_bar(cnt, (unsigned)NORM_BLOCKS * bar);

        // phase 2: this block reduces rows {2d, 2d+1} over its direction's 64 P buffers
        {
            int r = tid >> 7;
            int j = tid & 127;
            int row = 2 * d + r;
            float a = 0.f;
            const float* p0 = Pgrp + (size_t)row * BD + j;
            #pragma unroll 8
            for (int dd = 0; dd < 64; ++dd) a += p0[(size_t)dd * (BD * BD)];
            stateG[row * BD + j] = f2bf(a * (1.0f / 64.0f));   // exact /64 rescale per step
        }

        ++bar; grid_bar(cnt, (unsigned)NORM_BLOCKS * bar);
    }
}

// ---- batch kernel: one chain per block, fp32. 64-row LDS staging halves with
// register prefetch of the next half/step (x_t known in advance, no data dependence).
__global__ __launch_bounds__(256, 1) void mps_batch(const int* __restrict__ xs,
                                                    const float* __restrict__ core,
                                                    const float* __restrict__ edge,
                                                    unsigned char* __restrict__ ws) {
    __shared__ float Ab[64 * 129];
    __shared__ float h[BD], hn[BD];
    __shared__ float part[4][64];
    __shared__ int xloc[SEQ];
    __shared__ float rr[256];
    float* psi2 = (float*)(ws + WS_PSI);
    const int tid = threadIdx.x;
    const int b = blockIdx.x;

    for (int i = tid; i < SEQ; i += 256) xloc[i] = xs[(size_t)i * NB + b];
    if (tid < BD) h[tid] = edge[tid];          // h0 = alpha
    __syncthreads();

    float4v vA[8];
    {
        const float4v* s4 = (const float4v*)(core + ((size_t)xloc[0] << 14));
        #pragma unroll
        for (int s2 = 0; s2 < 8; ++s2) vA[s2] = s4[s2 * 256 + tid];
    }
    for (int t = 0; t < SEQ; ++t) {
        #pragma unroll
        for (int half = 0; half < 2; ++half) {
            #pragma unroll
            for (int s2 = 0; s2 < 8; ++s2) {    // drain prefetched regs into LDS
                int f = s2 * 256 + tid;          // float4 idx in 64x128 chunk
                int i = f >> 5;
                int j = (f & 31) << 2;
                float* dst = Ab + i * 129 + j;
                float4v v = vA[s2];
                dst[0] = v.x; dst[1] = v.y; dst[2] = v.z; dst[3] = v.w;
            }
            __syncthreads();
            {   // issue next chunk's loads (overlaps compute below)
                int nt = t + half;               // half0 -> (t,1), half1 -> (t+1,0)
                int nh = half ^ 1;
                if (nt < SEQ) {
                    const float4v* s4 = (const float4v*)(core + ((size_t)(nt * IDIM + xloc[nt]) << 14) + nh * 8192);
                    #pragma unroll
                    for (int s2 = 0; s2 < 8; ++s2) vA[s2] = s4[s2 * 256 + tid];
                }
            }
            {   // h'[64*half + r] = sum_k A[64*half + r][k] * h[k]
                int r = tid & 63, qq = tid >> 6;
                const float* row = Ab + r * 129 + qq * 32;
                const float* hh = h + qq * 32;
                float a = 0.f;
                #pragma unroll
                for (int k = 0; k < 32; ++k) a += row[k] * hh[k];
                part[qq][r] = a;
            }
            __syncthreads();
            if (tid < 64) hn[half * 64 + tid] = part[0][tid] + part[1][tid] + part[2][tid] + part[3][tid];
            __syncthreads();
        }
        if (tid < BD) h[tid] = hn[tid];
        __syncthreads();
    }
    float v = (tid < BD) ? h[tid] * edge[BD + tid] : 0.f;   // psi = h . omega
    rr[tid] = v; __syncthreads();
    for (int off = 128; off > 0; off >>= 1) { if (tid < off) rr[tid] += rr[tid + off]; __syncthreads(); }
    if (tid == 0) psi2[b] = 2.0f * logf(fabsf(rr[0]));
}

__global__ void mps_final(unsigned char* __restrict__ ws, float* __restrict__ out) {
    const ushort_t* rho = (const ushort_t*)(ws + WS_RHO);
    const ushort_t* sig = (const ushort_t*)(ws + WS_SIG);
    const float* psi2 = (const float*)(ws + WS_PSI);
    __shared__ float rr[256];
    __shared__ float logn_s;
    int tid = threadIdx.x;
    float a = 0.f;
    for (int i = tid; i < BD * BD; i += 256) a += bf2f(rho[i]) * bf2f(sig[i]);
    rr[tid] = a; __syncthreads();
    for (int off = 128; off > 0; off >>= 1) { if (tid < off) rr[tid] += rr[tid + off]; __syncthreads(); }
    if (tid == 0) logn_s = logf(rr[0]) + 256.0f * logf(64.0f);  // Z = tr(rho~ sig~) * 64^256
    __syncthreads();
    out[tid] = psi2[tid] - logn_s;
}

extern "C" void kernel_launch(void* const* d_in, const int* in_sizes, int n_in,
                              void* d_out, int out_size, void* d_ws, size_t ws_size,
                              hipStream_t stream) {
    const int* xs = (const int*)d_in[0];
    const float* core = (const float*)d_in[1];
    const float* edge = (const float*)d_in[2];
    unsigned char* ws = (unsigned char*)d_ws;
    float* out = (float*)d_out;

    const int norm_lds = 3 * BD * TS * 2;   // 104448 B dynamic LDS (>64KiB needs opt-in)
    (void)hipFuncSetAttribute(reinterpret_cast<const void*>(mps_norm),
                              hipFuncAttributeMaxDynamicSharedMemorySize, norm_lds);

    mps_init<<<1, 256, 0, stream>>>(edge, ws);
    mps_norm<<<NORM_BLOCKS, 256, norm_lds, stream>>>(core, ws);
    mps_batch<<<NB, 256, 0, stream>>>(xs, core, edge, ws);
    mps_final<<<1, 256, 0, stream>>>(ws, out);
}